// Round 7
// baseline (701.910 us; speedup 1.0000x reference)
//
#include <hip/hip_runtime.h>
#include <stdint.h>

#define NUSER 200000
#define NREPO 100000
#define NEDGE 1500000

#define RB 98        // repo buckets (dst>>10)
#define UB 196       // user buckets (dst>>10)
#define RCAP 17500   // per-bucket record capacity (mean 15360, +17 sigma)
#define UCAP 9000    // per-bucket record capacity (mean 7680, +15 sigma)

typedef unsigned short u16;
typedef unsigned int u32;
typedef __bf16 bf16x8 __attribute__((ext_vector_type(8)));
typedef float f32x4 __attribute__((ext_vector_type(4)));

// ---- workspace layout (bytes) ----
// Each feature table has ONE extra zeroed row (index N) used by the gather's
// branchless tail (idx -> zero row instead of mask-ANDs). Zero rows + CSR
// counters are (re)initialized by init_kernel every launch (ws is poisoned).
// records overlay the B0 region: dead before gathers write B0/B1.
#define OFF_RECR 0UL            //  6,860,000  u32[98*17500]
#define OFF_RECU 6860000UL      //  7,056,000  u32[196*9000]
#define OFF_B0   0UL            // 51,200,256  mean_u -> hu (bf16 200001x128)
#define OFF_B1   51200256UL     // 25,600,256  mean_r -> hr (100001 rows)
#define OFF_B2   76800512UL     // 51,200,256  xu_bf ; later mean_u2
#define OFF_B3   128000768UL    // 25,600,256  xr_bf ; later mean_r2
#define OFF_COLR 153601024UL    //  6,000,000
#define OFF_COLU 159601024UL    //  6,000,000
#define OFF_POSR 165601024UL    //    400,000
#define OFF_POSU 166001024UL    //    800,000
#define OFF_WT   166801024UL    //    262,144  4 x [128n][256k] bf16
#define OFF_CUR  167063168UL    //  gcur_r(400) gcur_u(800) cb_r(400) cb_u(800)
#define WS_NEEDED 167065568UL

// zero-row byte offsets (row N of each table)
#define ZR_B0 (OFF_B0 + 51200000UL)
#define ZR_B1 (OFF_B1 + 25600000UL)
#define ZR_B2 (OFF_B2 + 51200000UL)
#define ZR_B3 (OFF_B3 + 25600000UL)

__device__ __forceinline__ float bflo(u32 p) { return __uint_as_float(p << 16); }
__device__ __forceinline__ float bfhi(u32 p) { return __uint_as_float(p & 0xffff0000u); }
__device__ __forceinline__ u16 f2bf(float f) {
    u32 u = __float_as_uint(f);
    return (u16)((u + 0x7fffu + ((u >> 16) & 1u)) >> 16);
}
__device__ __forceinline__ bf16x8 as_bf16x8(uint4 u) {
    union { uint4 a; bf16x8 b; } x; x.a = u; return x.b;
}

__global__ void sentinel_kernel(float* out) { out[threadIdx.x] = 1234.5f; }

// zero CSR counters + the 4 feature-table zero rows (re-done every launch)
__global__ void init_kernel(char* __restrict__ ws) {
    int t = threadIdx.x;
    int* g = (int*)(ws + OFF_CUR);
    if (t < 300) g[t] = 0;
    if (t < 64) {
        ((u32*)(ws + ZR_B0))[t] = 0;
        ((u32*)(ws + ZR_B1))[t] = 0;
        ((u32*)(ws + ZR_B2))[t] = 0;
        ((u32*)(ws + ZR_B3))[t] = 0;
    }
}

// fp32 -> bf16 (packed), 4 elems/thread, both tables in one grid
__global__ void cvt_bf16_both(const float4* __restrict__ inA, uint2* __restrict__ outA, int n4A,
                              const float4* __restrict__ inB, uint2* __restrict__ outB, int n4B) {
    int i = blockIdx.x * blockDim.x + threadIdx.x;
    const float4* in; uint2* out; int idx;
    if (i < n4A) { in = inA; out = outA; idx = i; }
    else { in = inB; out = outB; idx = i - n4A; if (idx >= n4B) return; }
    float4 v = in[idx];
    uint2 o;
    o.x = (u32)f2bf(v.x) | ((u32)f2bf(v.y) << 16);
    o.y = (u32)f2bf(v.z) | ((u32)f2bf(v.w) << 16);
    out[idx] = o;
}

// All four weight pairs in one grid: Wt[set][n*256+k] = bf16(k<128 ? Wl[k][n] : Wr[k-128][n])
__global__ void wprep4_kernel(const float* __restrict__ Wl0, const float* __restrict__ Wr0,
                              const float* __restrict__ Wl1, const float* __restrict__ Wr1,
                              const float* __restrict__ Wl2, const float* __restrict__ Wr2,
                              const float* __restrict__ Wl3, const float* __restrict__ Wr3,
                              u16* __restrict__ Wt) {
    int which = blockIdx.x >> 7;
    const float* Wl = (which == 0) ? Wl0 : (which == 1) ? Wl1 : (which == 2) ? Wl2 : Wl3;
    const float* Wr = (which == 0) ? Wr0 : (which == 1) ? Wr1 : (which == 2) ? Wr2 : Wr3;
    int idx = (blockIdx.x & 127) * 256 + threadIdx.x;
    int n = idx >> 8, k = idx & 255;
    float v = (k < 128) ? Wl[k * 128 + n] : Wr[(k - 128) * 128 + n];
    Wt[which * 32768 + idx] = f2bf(v);
}

// int64/int32-robust edge decode flag (first 2048 words, L2-hot)
__device__ __forceinline__ bool detect_is64(const u32* e) {
    __shared__ int any_odd;
    int t = threadIdx.x;
    if (t == 0) any_odd = 0;
    __syncthreads();
    u32 acc = 0;
#pragma unroll
    for (int r = 0; r < 4; ++r) acc |= e[2 * (256 * r + t) + 1];
    if (acc != 0) any_odd = 1;
    __syncthreads();
    return !any_odd;
}

// Pass A: bin edges by dst>>10 into per-bucket record regions (both
// directions in one pass). 1024 edges/block (4x more blocks than before:
// less per-block LDS-atomic serialization, 5.7 blocks/CU). Per-block LDS
// histogram -> one global atomicAdd per (block,bucket) -> dense runs of
// packed records (src<<10 | dst&1023).
__global__ __launch_bounds__(256)
void passA_bin(const u32* __restrict__ e, u32* __restrict__ rec_r, u32* __restrict__ rec_u,
               int* __restrict__ gcur_r, int* __restrict__ gcur_u) {
    __shared__ int cntR[RB], cntU[UB], baseR[RB], baseU[UB];
    bool is64 = detect_is64(e);
    int t = threadIdx.x;
    for (int i = t; i < RB; i += 256) cntR[i] = 0;
    for (int i = t; i < UB; i += 256) cntU[i] = 0;
    __syncthreads();
    int base = blockIdx.x * 1024;
    int us[4], rs[4];
#pragma unroll
    for (int j = 0; j < 4; ++j) {
        int i = base + j * 256 + t;
        int u = -1, r = -1;
        if (i < NEDGE) {
            u = is64 ? (int)e[2 * i] : (int)e[i];
            r = is64 ? (int)e[2 * (NEDGE + i)] : (int)e[NEDGE + i];
        }
        us[j] = u; rs[j] = r;
        if (u >= 0) { atomicAdd(&cntR[r >> 10], 1); atomicAdd(&cntU[u >> 10], 1); }
    }
    __syncthreads();
    for (int i = t; i < RB; i += 256) baseR[i] = cntR[i] ? atomicAdd(&gcur_r[i], cntR[i]) : 0;
    for (int i = t; i < UB; i += 256) baseU[i] = cntU[i] ? atomicAdd(&gcur_u[i], cntU[i]) : 0;
    __syncthreads();
    for (int i = t; i < RB; i += 256) cntR[i] = 0;
    for (int i = t; i < UB; i += 256) cntU[i] = 0;
    __syncthreads();
#pragma unroll
    for (int j = 0; j < 4; ++j) {
        int u = us[j], r = rs[j];
        if (u >= 0) {
            int br = r >> 10, bu = u >> 10;
            int rk = baseR[br] + atomicAdd(&cntR[br], 1);
            if (rk < RCAP) rec_r[br * RCAP + rk] = ((u32)u << 10) | (u32)(r & 1023);
            int ku = baseU[bu] + atomicAdd(&cntU[bu], 1);
            if (ku < UCAP) rec_u[bu * UCAP + ku] = ((u32)r << 10) | (u32)(u & 1023);
        }
    }
}

// exclusive scan of bucket sizes -> dense col base per bucket (one block)
__global__ void bucket_scan(const int* __restrict__ gcur_r, const int* __restrict__ gcur_u,
                            int* __restrict__ cb_r, int* __restrict__ cb_u) {
    __shared__ int s0[256], s1[256];
    int t = threadIdx.x;
    // repo
    s0[t] = (t < RB) ? min(gcur_r[t], RCAP) : 0;
    __syncthreads();
    int* src = s0; int* dst = s1;
    for (int off = 1; off < 256; off <<= 1) {
        int x = src[t]; if (t >= off) x += src[t - off];
        dst[t] = x; __syncthreads();
        int* tmp = src; src = dst; dst = tmp;
    }
    if (t < RB) cb_r[t] = (t == 0) ? 0 : src[t - 1];
    __syncthreads();
    // user
    src[t] = 0; __syncthreads();   // normalize: reuse s-arrays
    s0[t] = (t < UB) ? min(gcur_u[t], UCAP) : 0;
    __syncthreads();
    src = s0; dst = s1;
    for (int off = 1; off < 256; off <<= 1) {
        int x = src[t]; if (t >= off) x += src[t - off];
        dst[t] = x; __syncthreads();
        int* tmp = src; src = dst; dst = tmp;
    }
    if (t < UB) cb_u[t] = (t == 0) ? 0 : src[t - 1];
}

// Pass B: one block per bucket. Count local dsts in LDS, block-scan, write
// pos (inclusive ends, global col coords) sequentially, then scatter col —
// random writes confined to a ~60KB L2-resident window (~1x amplification).
__global__ __launch_bounds__(256)
void passB_build(const u32* __restrict__ rec_r, const u32* __restrict__ rec_u,
                 const int* __restrict__ gcur_r, const int* __restrict__ gcur_u,
                 const int* __restrict__ cb_r, const int* __restrict__ cb_u,
                 int* __restrict__ col_r, int* __restrict__ col_u,
                 int* __restrict__ pos_r, int* __restrict__ pos_u) {
    __shared__ int cnt[1024];
    __shared__ int excl[1024];
    __shared__ int sc0[256], sc1[256];
    int b = blockIdx.x;
    const u32* rec; int count, colbase, dstbase, ndst; int* col; int* pos;
    if (b < RB) {
        rec = rec_r + (size_t)b * RCAP; count = min(gcur_r[b], RCAP); colbase = cb_r[b];
        dstbase = b << 10; ndst = min(1024, NREPO - dstbase); col = col_r; pos = pos_r;
    } else {
        int c = b - RB;
        rec = rec_u + (size_t)c * UCAP; count = min(gcur_u[c], UCAP); colbase = cb_u[c];
        dstbase = c << 10; ndst = min(1024, NUSER - dstbase); col = col_u; pos = pos_u;
    }
    int t = threadIdx.x;
    for (int i = t; i < 1024; i += 256) cnt[i] = 0;
    __syncthreads();
    for (int i = t; i < count; i += 256) atomicAdd(&cnt[rec[i] & 1023], 1);
    __syncthreads();
    int c0 = cnt[t * 4], c1 = cnt[t * 4 + 1], c2 = cnt[t * 4 + 2], c3 = cnt[t * 4 + 3];
    int tsum = c0 + c1 + c2 + c3;
    sc0[t] = tsum; __syncthreads();
    int* src = sc0; int* dst = sc1;
    for (int off = 1; off < 256; off <<= 1) {
        int x = src[t]; if (t >= off) x += src[t - off];
        dst[t] = x; __syncthreads();
        int* tmp = src; src = dst; dst = tmp;
    }
    int exclT = src[t] - tsum;
    int e0 = exclT, e1 = e0 + c0, e2 = e1 + c1, e3 = e2 + c2;
    excl[t * 4] = e0; excl[t * 4 + 1] = e1; excl[t * 4 + 2] = e2; excl[t * 4 + 3] = e3;
    // pos = inclusive ends in global col coords (sequential writes)
    {
        int i = t * 4;
        if (i < ndst)     pos[dstbase + i]     = colbase + e1;
        if (i + 1 < ndst) pos[dstbase + i + 1] = colbase + e2;
        if (i + 2 < ndst) pos[dstbase + i + 2] = colbase + e3;
        if (i + 3 < ndst) pos[dstbase + i + 3] = colbase + e3 + c3;
    }
    __syncthreads();
    for (int i = t; i < 1024; i += 256) cnt[i] = 0;
    __syncthreads();
    for (int i = t; i < count; i += 256) {
        u32 rc = rec[i];
        int dl = rc & 1023;
        int rk = atomicAdd(&cnt[dl], 1);
        col[colbase + excl[dl] + rk] = (int)(rc >> 10);
    }
}

// Gather-mean, TWO destinations per wave (32 lanes each), both node sides in
// one grid. Per destination: 2 groups x 16 lanes; each lane reads 16 B of an
// edge-row; 4 loads in flight per lane (8 edges/dest/iteration).
// Edge indices come from DIRECT L1-hot col[] loads (all 16 lanes of a group
// hit the same 64-B line) instead of ds_bpermute shuffles — the col loads of
// iteration k+1 are independent of iteration k's feature loads, so they
// pipeline under vmcnt instead of serializing on the LDS pipe. Out-of-segment
// indices read adjacent valid memory and are cndmask'd to the ZERO ROW
// (exact 0.0f contribution; FP summation order identical to prior rounds).
// Single shfl_xor(16) reduce; group 0 packs bf16 out.
__global__ __launch_bounds__(256)
void gather_mean2(const u16* __restrict__ featA, const int* __restrict__ colA,
                  const int* __restrict__ posA, u16* __restrict__ outA, int ndstA, int nwaveA, int zrowA,
                  const u16* __restrict__ featB, const int* __restrict__ colB,
                  const int* __restrict__ posB, u16* __restrict__ outB, int ndstB, int zrowB) {
    int gw = (blockIdx.x * blockDim.x + threadIdx.x) >> 6;
    const u16* feat; const int* col; const int* pos; u16* outm; int ndst, dbase, zrow;
    if (gw < nwaveA) {
        feat = featA; col = colA; pos = posA; outm = outA; ndst = ndstA; dbase = gw * 2; zrow = zrowA;
    } else {
        feat = featB; col = colB; pos = posB; outm = outB; ndst = ndstB; dbase = (gw - nwaveA) * 2; zrow = zrowB;
    }
    int lane = threadIdx.x & 63;
    int h = lane >> 5, l5 = lane & 31, g2 = l5 >> 4, s = l5 & 15;
    int d = dbase + h;
    if (d >= ndst) return;

    int start = (d == 0) ? 0 : pos[d - 1];
    int end = pos[d];
    int deg = end - start;

    float acc[8];
#pragma unroll
    for (int k = 0; k < 8; ++k) acc[k] = 0.f;

#define LDROW(idx) (*(const uint4*)(feat + (size_t)(idx) * 128 + s * 8))
#define ACC4(a, b, c, dd) \
    acc[0] += (bflo(a.x) + bflo(b.x)) + (bflo(c.x) + bflo(dd.x)); \
    acc[1] += (bfhi(a.x) + bfhi(b.x)) + (bfhi(c.x) + bfhi(dd.x)); \
    acc[2] += (bflo(a.y) + bflo(b.y)) + (bflo(c.y) + bflo(dd.y)); \
    acc[3] += (bfhi(a.y) + bfhi(b.y)) + (bfhi(c.y) + bfhi(dd.y)); \
    acc[4] += (bflo(a.z) + bflo(b.z)) + (bflo(c.z) + bflo(dd.z)); \
    acc[5] += (bfhi(a.z) + bfhi(b.z)) + (bfhi(c.z) + bfhi(dd.z)); \
    acc[6] += (bflo(a.w) + bflo(b.w)) + (bflo(c.w) + bflo(dd.w)); \
    acc[7] += (bfhi(a.w) + bfhi(b.w)) + (bfhi(c.w) + bfhi(dd.w));

    if (deg > 0) {
        int mdeg = min(deg, 32);
        const int* cbase = col + start;
        for (int e0 = 0; e0 < mdeg; e0 += 8) {
            int i0 = e0 + g2, i1 = e0 + 2 + g2, i2 = e0 + 4 + g2, i3 = e0 + 6 + g2;
            // reads beyond the segment (i >= deg, i < 32) land in the next
            // segment / adjacent arrays — valid memory, replaced by zrow.
            int t0 = cbase[i0], t1 = cbase[i1], t2 = cbase[i2], t3 = cbase[i3];
            int x0 = (i0 < deg) ? t0 : zrow, x1 = (i1 < deg) ? t1 : zrow;
            int x2 = (i2 < deg) ? t2 : zrow, x3 = (i3 < deg) ? t3 : zrow;
            uint4 v0 = LDROW(x0), v1 = LDROW(x1), v2 = LDROW(x2), v3 = LDROW(x3);
            ACC4(v0, v1, v2, v3)
        }
        // rare path: degrees beyond 32 (repo tail of Poisson(15))
        for (int e = 32 + g2; e < deg; e += 2) {
            int idx = cbase[e];
            uint4 v = LDROW(idx);
            acc[0] += bflo(v.x); acc[1] += bfhi(v.x);
            acc[2] += bflo(v.y); acc[3] += bfhi(v.y);
            acc[4] += bflo(v.z); acc[5] += bfhi(v.z);
            acc[6] += bflo(v.w); acc[7] += bfhi(v.w);
        }
        // combine the 2 group partials within each 32-lane half
#pragma unroll
        for (int k = 0; k < 8; ++k) acc[k] += __shfl_xor(acc[k], 16, 64);
    }
#undef LDROW
#undef ACC4

    if (g2 == 0) {
        float inv = (deg > 0) ? 1.0f / (float)deg : 0.f;
        uint4 o;
        o.x = (u32)f2bf(acc[0] * inv) | ((u32)f2bf(acc[1] * inv) << 16);
        o.y = (u32)f2bf(acc[2] * inv) | ((u32)f2bf(acc[3] * inv) << 16);
        o.z = (u32)f2bf(acc[4] * inv) | ((u32)f2bf(acc[5] * inv) << 16);
        o.w = (u32)f2bf(acc[6] * inv) | ((u32)f2bf(acc[7] * inv) << 16);
        *(uint4*)(outm + (size_t)d * 128 + s * 8) = o;
    }
}

// MFMA transform, both node sides in one grid, TILES_PER_BLK row-tiles per
// block: weight fragments + bias loaded ONCE per block (reloaded only at the
// single side-straddle block) — 4x less weight L2 traffic and 4x fewer
// block-start latencies than one-tile blocks.
// out[N x 128] = [mean|x] @ [Wl;Wr] + bias (opt relu).
#define TILES_PER_BLK 4
__global__ __launch_bounds__(256)
void transform_both(const u16* __restrict__ A_A, const u16* __restrict__ X_A,
                    const u16* __restrict__ Wt_A, const float* __restrict__ b_A,
                    u16* __restrict__ obf_A, float* __restrict__ of32_A, int N_A, int nblkA,
                    const u16* __restrict__ A_B, const u16* __restrict__ X_B,
                    const u16* __restrict__ Wt_B, const float* __restrict__ b_B,
                    u16* __restrict__ obf_B, float* __restrict__ of32_B, int N_B, int nblkB,
                    int do_relu) {
    __shared__ __align__(16) u16 sA[64][264];
    int tid = threadIdx.x;
    int w = tid >> 6, lane = tid & 63;
    int q = lane >> 4, n = lane & 15;
    int nb = w * 32;
    int r_st = tid >> 2, c_st = tid & 3;

    bf16x8 bfrag[2][8];
    float bv[2];
    int prev_side = -1;

    int tile0 = blockIdx.x * TILES_PER_BLK;
    int ntile = nblkA + nblkB;
    for (int ti = 0; ti < TILES_PER_BLK; ++ti) {
        int tile = tile0 + ti;
        if (tile >= ntile) break;
        int side = (tile < nblkA) ? 0 : 1;
        const u16* A; const u16* X; const u16* Wt; const float* bias;
        u16* out_bf; float* out_f32; int N, base;
        if (side == 0) {
            A = A_A; X = X_A; Wt = Wt_A; bias = b_A; out_bf = obf_A; out_f32 = of32_A;
            N = N_A; base = tile * 64;
        } else {
            A = A_B; X = X_B; Wt = Wt_B; bias = b_B; out_bf = obf_B; out_f32 = of32_B;
            N = N_B; base = (tile - nblkA) * 64;
        }

        if (side != prev_side) {
            prev_side = side;
#pragma unroll
            for (int nt = 0; nt < 2; ++nt)
#pragma unroll
                for (int ks = 0; ks < 8; ++ks)
                    bfrag[nt][ks] = as_bf16x8(*(const uint4*)(Wt + (size_t)(nb + nt * 16 + n) * 256 + ks * 32 + q * 8));
            bv[0] = bias[nb + n]; bv[1] = bias[nb + 16 + n];
        }

        if (ti > 0) __syncthreads();   // prev tile's LDS readers done
        {
            int node = base + r_st;
            uint4 z = make_uint4(0, 0, 0, 0);
            uint4 va[4], vx[4];
            if (node < N) {
                const uint4* pa = (const uint4*)(A + (size_t)node * 128 + c_st * 32);
                const uint4* px = (const uint4*)(X + (size_t)node * 128 + c_st * 32);
#pragma unroll
                for (int j = 0; j < 4; ++j) { va[j] = pa[j]; vx[j] = px[j]; }
            } else {
#pragma unroll
                for (int j = 0; j < 4; ++j) { va[j] = z; vx[j] = z; }
            }
#pragma unroll
            for (int j = 0; j < 4; ++j) {
                *(uint4*)&sA[r_st][c_st * 32 + j * 8] = va[j];
                *(uint4*)&sA[r_st][128 + c_st * 32 + j * 8] = vx[j];
            }
        }
        __syncthreads();

        f32x4 zz = { 0.f, 0.f, 0.f, 0.f };
        f32x4 acc[4][2];
#pragma unroll
        for (int mt = 0; mt < 4; ++mt) { acc[mt][0] = zz; acc[mt][1] = zz; }

#pragma unroll
        for (int ks = 0; ks < 8; ++ks)
#pragma unroll
            for (int mt = 0; mt < 4; ++mt) {
                bf16x8 af = *(const bf16x8*)&sA[mt * 16 + n][ks * 32 + q * 8];
                acc[mt][0] = __builtin_amdgcn_mfma_f32_16x16x32_bf16(af, bfrag[0][ks], acc[mt][0], 0, 0, 0);
                acc[mt][1] = __builtin_amdgcn_mfma_f32_16x16x32_bf16(af, bfrag[1][ks], acc[mt][1], 0, 0, 0);
            }

#pragma unroll
        for (int mt = 0; mt < 4; ++mt) {
            int row0 = base + mt * 16 + q * 4;
#pragma unroll
            for (int nt = 0; nt < 2; ++nt) {
                int colg = nb + nt * 16 + n;
#pragma unroll
                for (int r = 0; r < 4; ++r) {
                    int row = row0 + r;
                    if (row < N) {
                        float v = acc[mt][nt][r] + bv[nt];
                        if (do_relu) v = fmaxf(v, 0.f);
                        if (out_bf) out_bf[(size_t)row * 128 + colg] = f2bf(v);
                        else        out_f32[(size_t)row * 128 + colg] = v;
                    }
                }
            }
        }
    }
}

extern "C" void kernel_launch(void* const* d_in, const int* in_sizes, int n_in,
                              void* d_out, int out_size, void* d_ws, size_t ws_size,
                              hipStream_t stream) {
    const float* x_user = (const float*)d_in[0];
    const float* x_repo = (const float*)d_in[1];
    const u32* edges = (const u32*)d_in[2];
    const float* Wl1s = (const float*)d_in[3], *bl1s = (const float*)d_in[4], *Wr1s = (const float*)d_in[5];
    const float* Wl1r = (const float*)d_in[6], *bl1r = (const float*)d_in[7], *Wr1r = (const float*)d_in[8];
    const float* Wl2s = (const float*)d_in[9], *bl2s = (const float*)d_in[10], *Wr2s = (const float*)d_in[11];
    const float* Wl2r = (const float*)d_in[12], *bl2r = (const float*)d_in[13], *Wr2r = (const float*)d_in[14];

    float* out_user = (float*)d_out;
    float* out_repo = (float*)d_out + (size_t)NUSER * 128;

    if (ws_size < WS_NEEDED) {
        hipLaunchKernelGGL(sentinel_kernel, dim3(1), dim3(256), 0, stream, out_user);
        return;
    }

    char* ws = (char*)d_ws;
    u32* rec_r = (u32*)(ws + OFF_RECR);
    u32* rec_u = (u32*)(ws + OFF_RECU);
    u16* B0 = (u16*)(ws + OFF_B0);
    u16* B1 = (u16*)(ws + OFF_B1);
    u16* B2 = (u16*)(ws + OFF_B2);
    u16* B3 = (u16*)(ws + OFF_B3);
    int* col_r = (int*)(ws + OFF_COLR);
    int* col_u = (int*)(ws + OFF_COLU);
    int* pos_r = (int*)(ws + OFF_POSR);
    int* pos_u = (int*)(ws + OFF_POSU);
    u16* wt1s = (u16*)(ws + OFF_WT);
    u16* wt1r = wt1s + 32768;
    u16* wt2s = wt1r + 32768;
    u16* wt2r = wt2s + 32768;
    int* gcur_r = (int*)(ws + OFF_CUR);          // 400 B
    int* gcur_u = (int*)(ws + OFF_CUR + 400);    // 800 B
    int* cb_r   = (int*)(ws + OFF_CUR + 1200);   // 400 B
    int* cb_u   = (int*)(ws + OFF_CUR + 1600);   // 800 B

    const int nblkR = (NREPO + 63) / 64;   // 1563
    const int nblkU = (NUSER + 63) / 64;   // 3125
    const int ntile = nblkR + nblkU;       // 4688
    const int tblk = (ntile + TILES_PER_BLK - 1) / TILES_PER_BLK;  // 1172
    const int nwaveR = NREPO / 2;          // 50000 (2 dests/wave)
    const int nwaveU = NUSER / 2;          // 100000
    const int gblk = (nwaveR + nwaveU) / 4;  // 37500 blocks, 4 waves each

    // init (CSR counters + zero rows), then CSR build (binned, L2-confined scatter)
    hipLaunchKernelGGL(init_kernel, dim3(1), dim3(320), 0, stream, ws);
    hipLaunchKernelGGL(passA_bin, dim3((NEDGE + 1023) / 1024), dim3(256), 0, stream,
                       edges, rec_r, rec_u, gcur_r, gcur_u);
    hipLaunchKernelGGL(bucket_scan, dim3(1), dim3(256), 0, stream, gcur_r, gcur_u, cb_r, cb_u);
    hipLaunchKernelGGL(passB_build, dim3(RB + UB), dim3(256), 0, stream,
                       rec_r, rec_u, gcur_r, gcur_u, cb_r, cb_u, col_r, col_u, pos_r, pos_u);

    // weight prep + input converts (records dead from here; B-regions live)
    hipLaunchKernelGGL(wprep4_kernel, dim3(512), dim3(256), 0, stream,
                       Wl1s, Wr1s, Wl1r, Wr1r, Wl2s, Wr2s, Wl2r, Wr2r, wt1s);
    hipLaunchKernelGGL(cvt_bf16_both, dim3(37500), dim3(256), 0, stream,
                       (const float4*)x_user, (uint2*)B2, NUSER * 128 / 4,
                       (const float4*)x_repo, (uint2*)B3, NREPO * 128 / 4);

    // Layer 1: merged gathers, merged transforms (in-place mean -> hidden, relu)
    hipLaunchKernelGGL(gather_mean2, dim3(gblk), dim3(256), 0, stream,
                       B2, col_r, pos_r, B1, NREPO, nwaveR, NUSER,
                       B3, col_u, pos_u, B0, NUSER, NREPO);
    hipLaunchKernelGGL(transform_both, dim3(tblk), dim3(256), 0, stream,
                       B1, B3, wt1s, bl1s, B1, (float*)nullptr, NREPO, nblkR,
                       B0, B2, wt1r, bl1r, B0, (float*)nullptr, NUSER, nblkU,
                       1);

    // Layer 2: gathers over hiddens, transforms write fp32 d_out
    hipLaunchKernelGGL(gather_mean2, dim3(gblk), dim3(256), 0, stream,
                       B0, col_r, pos_r, B3, NREPO, nwaveR, NUSER,
                       B1, col_u, pos_u, B2, NUSER, NREPO);
    hipLaunchKernelGGL(transform_both, dim3(tblk), dim3(256), 0, stream,
                       B3, B1, wt2s, bl2s, (u16*)nullptr, out_repo, NREPO, nblkR,
                       B2, B0, wt2r, bl2r, (u16*)nullptr, out_user, NUSER, nblkU,
                       0);
}

// Round 8
// 679.504 us; speedup vs baseline: 1.0330x; 1.0330x over previous
//
#include <hip/hip_runtime.h>
#include <stdint.h>

#define NUSER 200000
#define NREPO 100000
#define NEDGE 1500000

#define RB 98        // repo buckets (dst>>10)
#define UB 196       // user buckets (dst>>10)
#define RCAP 17500   // per-bucket record capacity (mean 15360, +17 sigma)
#define UCAP 9000    // per-bucket record capacity (mean 7680, +15 sigma)

typedef unsigned short u16;
typedef unsigned int u32;
typedef __bf16 bf16x8 __attribute__((ext_vector_type(8)));
typedef float f32x4 __attribute__((ext_vector_type(4)));

// ---- workspace layout (bytes) ----
// Each feature table has ONE extra zeroed row (index N) used by the gather's
// branchless tail (idx -> zero row instead of mask-ANDs). Zero rows + CSR
// counters are (re)initialized by init_kernel every launch (ws is poisoned).
// records overlay the B0 region: dead before gathers write B0/B1.
#define OFF_RECR 0UL            //  6,860,000  u32[98*17500]
#define OFF_RECU 6860000UL      //  7,056,000  u32[196*9000]
#define OFF_B0   0UL            // 51,200,256  mean_u -> hu (bf16 200001x128)
#define OFF_B1   51200256UL     // 25,600,256  mean_r -> hr (100001 rows)
#define OFF_B2   76800512UL     // 51,200,256  xu_bf ; later mean_u2
#define OFF_B3   128000768UL    // 25,600,256  xr_bf ; later mean_r2
#define OFF_COLR 153601024UL    //  6,000,000
#define OFF_COLU 159601024UL    //  6,000,000
#define OFF_POSR 165601024UL    //    400,000
#define OFF_POSU 166001024UL    //    800,000
#define OFF_WT   166801024UL    //    262,144  4 x [128n][256k] bf16
#define OFF_CUR  167063168UL    //  gcur_r(400) gcur_u(800) cb_r(400) cb_u(800)
#define WS_NEEDED 167065568UL

// zero-row byte offsets (row N of each table)
#define ZR_B0 (OFF_B0 + 51200000UL)
#define ZR_B1 (OFF_B1 + 25600000UL)
#define ZR_B2 (OFF_B2 + 51200000UL)
#define ZR_B3 (OFF_B3 + 25600000UL)

__device__ __forceinline__ float bflo(u32 p) { return __uint_as_float(p << 16); }
__device__ __forceinline__ float bfhi(u32 p) { return __uint_as_float(p & 0xffff0000u); }
__device__ __forceinline__ u16 f2bf(float f) {
    u32 u = __float_as_uint(f);
    return (u16)((u + 0x7fffu + ((u >> 16) & 1u)) >> 16);
}
__device__ __forceinline__ bf16x8 as_bf16x8(uint4 u) {
    union { uint4 a; bf16x8 b; } x; x.a = u; return x.b;
}

__global__ void sentinel_kernel(float* out) { out[threadIdx.x] = 1234.5f; }

// zero CSR counters + the 4 feature-table zero rows (re-done every launch)
__global__ void init_kernel(char* __restrict__ ws) {
    int t = threadIdx.x;
    int* g = (int*)(ws + OFF_CUR);
    if (t < 300) g[t] = 0;
    if (t < 64) {
        ((u32*)(ws + ZR_B0))[t] = 0;
        ((u32*)(ws + ZR_B1))[t] = 0;
        ((u32*)(ws + ZR_B2))[t] = 0;
        ((u32*)(ws + ZR_B3))[t] = 0;
    }
}

// fp32 -> bf16 (packed), 4 elems/thread, both tables in one grid
__global__ void cvt_bf16_both(const float4* __restrict__ inA, uint2* __restrict__ outA, int n4A,
                              const float4* __restrict__ inB, uint2* __restrict__ outB, int n4B) {
    int i = blockIdx.x * blockDim.x + threadIdx.x;
    const float4* in; uint2* out; int idx;
    if (i < n4A) { in = inA; out = outA; idx = i; }
    else { in = inB; out = outB; idx = i - n4A; if (idx >= n4B) return; }
    float4 v = in[idx];
    uint2 o;
    o.x = (u32)f2bf(v.x) | ((u32)f2bf(v.y) << 16);
    o.y = (u32)f2bf(v.z) | ((u32)f2bf(v.w) << 16);
    out[idx] = o;
}

// All four weight pairs in one grid: Wt[set][n*256+k] = bf16(k<128 ? Wl[k][n] : Wr[k-128][n])
__global__ void wprep4_kernel(const float* __restrict__ Wl0, const float* __restrict__ Wr0,
                              const float* __restrict__ Wl1, const float* __restrict__ Wr1,
                              const float* __restrict__ Wl2, const float* __restrict__ Wr2,
                              const float* __restrict__ Wl3, const float* __restrict__ Wr3,
                              u16* __restrict__ Wt) {
    int which = blockIdx.x >> 7;
    const float* Wl = (which == 0) ? Wl0 : (which == 1) ? Wl1 : (which == 2) ? Wl2 : Wl3;
    const float* Wr = (which == 0) ? Wr0 : (which == 1) ? Wr1 : (which == 2) ? Wr2 : Wr3;
    int idx = (blockIdx.x & 127) * 256 + threadIdx.x;
    int n = idx >> 8, k = idx & 255;
    float v = (k < 128) ? Wl[k * 128 + n] : Wr[(k - 128) * 128 + n];
    Wt[which * 32768 + idx] = f2bf(v);
}

// int64/int32-robust edge decode flag (first 2048 words, L2-hot)
__device__ __forceinline__ bool detect_is64(const u32* e) {
    __shared__ int any_odd;
    int t = threadIdx.x;
    if (t == 0) any_odd = 0;
    __syncthreads();
    u32 acc = 0;
#pragma unroll
    for (int r = 0; r < 4; ++r) acc |= e[2 * (256 * r + t) + 1];
    if (acc != 0) any_odd = 1;
    __syncthreads();
    return !any_odd;
}

// Pass A: bin edges by dst>>10 into per-bucket record regions (both
// directions in one pass). 4096 edges/block (367 blocks: best measured —
// more blocks raises global-counter atomic contention + fixed costs).
// Per-block LDS histogram -> one global atomicAdd per (block,bucket) ->
// dense runs of packed records (src<<10 | dst&1023).
__global__ __launch_bounds__(256)
void passA_bin(const u32* __restrict__ e, u32* __restrict__ rec_r, u32* __restrict__ rec_u,
               int* __restrict__ gcur_r, int* __restrict__ gcur_u) {
    __shared__ int cntR[RB], cntU[UB], baseR[RB], baseU[UB];
    bool is64 = detect_is64(e);
    int t = threadIdx.x;
    for (int i = t; i < RB; i += 256) cntR[i] = 0;
    for (int i = t; i < UB; i += 256) cntU[i] = 0;
    __syncthreads();
    int base = blockIdx.x * 4096;
    int us[16], rs[16];
#pragma unroll
    for (int j = 0; j < 16; ++j) {
        int i = base + j * 256 + t;
        int u = -1, r = -1;
        if (i < NEDGE) {
            u = is64 ? (int)e[2 * i] : (int)e[i];
            r = is64 ? (int)e[2 * (NEDGE + i)] : (int)e[NEDGE + i];
        }
        us[j] = u; rs[j] = r;
        if (u >= 0) { atomicAdd(&cntR[r >> 10], 1); atomicAdd(&cntU[u >> 10], 1); }
    }
    __syncthreads();
    for (int i = t; i < RB; i += 256) baseR[i] = cntR[i] ? atomicAdd(&gcur_r[i], cntR[i]) : 0;
    for (int i = t; i < UB; i += 256) baseU[i] = cntU[i] ? atomicAdd(&gcur_u[i], cntU[i]) : 0;
    __syncthreads();
    for (int i = t; i < RB; i += 256) cntR[i] = 0;
    for (int i = t; i < UB; i += 256) cntU[i] = 0;
    __syncthreads();
#pragma unroll
    for (int j = 0; j < 16; ++j) {
        int u = us[j], r = rs[j];
        if (u >= 0) {
            int br = r >> 10, bu = u >> 10;
            int rk = baseR[br] + atomicAdd(&cntR[br], 1);
            if (rk < RCAP) rec_r[br * RCAP + rk] = ((u32)u << 10) | (u32)(r & 1023);
            int ku = baseU[bu] + atomicAdd(&cntU[bu], 1);
            if (ku < UCAP) rec_u[bu * UCAP + ku] = ((u32)r << 10) | (u32)(u & 1023);
        }
    }
}

// exclusive scan of bucket sizes -> dense col base per bucket (one block)
__global__ void bucket_scan(const int* __restrict__ gcur_r, const int* __restrict__ gcur_u,
                            int* __restrict__ cb_r, int* __restrict__ cb_u) {
    __shared__ int s0[256], s1[256];
    int t = threadIdx.x;
    // repo
    s0[t] = (t < RB) ? min(gcur_r[t], RCAP) : 0;
    __syncthreads();
    int* src = s0; int* dst = s1;
    for (int off = 1; off < 256; off <<= 1) {
        int x = src[t]; if (t >= off) x += src[t - off];
        dst[t] = x; __syncthreads();
        int* tmp = src; src = dst; dst = tmp;
    }
    if (t < RB) cb_r[t] = (t == 0) ? 0 : src[t - 1];
    __syncthreads();
    // user
    src[t] = 0; __syncthreads();   // normalize: reuse s-arrays
    s0[t] = (t < UB) ? min(gcur_u[t], UCAP) : 0;
    __syncthreads();
    src = s0; dst = s1;
    for (int off = 1; off < 256; off <<= 1) {
        int x = src[t]; if (t >= off) x += src[t - off];
        dst[t] = x; __syncthreads();
        int* tmp = src; src = dst; dst = tmp;
    }
    if (t < UB) cb_u[t] = (t == 0) ? 0 : src[t - 1];
}

// Pass B: one block per bucket. Count local dsts in LDS, block-scan, write
// pos (inclusive ends, global col coords) sequentially, then scatter col —
// random writes confined to a ~60KB L2-resident window (~1x amplification).
__global__ __launch_bounds__(256)
void passB_build(const u32* __restrict__ rec_r, const u32* __restrict__ rec_u,
                 const int* __restrict__ gcur_r, const int* __restrict__ gcur_u,
                 const int* __restrict__ cb_r, const int* __restrict__ cb_u,
                 int* __restrict__ col_r, int* __restrict__ col_u,
                 int* __restrict__ pos_r, int* __restrict__ pos_u) {
    __shared__ int cnt[1024];
    __shared__ int excl[1024];
    __shared__ int sc0[256], sc1[256];
    int b = blockIdx.x;
    const u32* rec; int count, colbase, dstbase, ndst; int* col; int* pos;
    if (b < RB) {
        rec = rec_r + (size_t)b * RCAP; count = min(gcur_r[b], RCAP); colbase = cb_r[b];
        dstbase = b << 10; ndst = min(1024, NREPO - dstbase); col = col_r; pos = pos_r;
    } else {
        int c = b - RB;
        rec = rec_u + (size_t)c * UCAP; count = min(gcur_u[c], UCAP); colbase = cb_u[c];
        dstbase = c << 10; ndst = min(1024, NUSER - dstbase); col = col_u; pos = pos_u;
    }
    int t = threadIdx.x;
    for (int i = t; i < 1024; i += 256) cnt[i] = 0;
    __syncthreads();
    for (int i = t; i < count; i += 256) atomicAdd(&cnt[rec[i] & 1023], 1);
    __syncthreads();
    int c0 = cnt[t * 4], c1 = cnt[t * 4 + 1], c2 = cnt[t * 4 + 2], c3 = cnt[t * 4 + 3];
    int tsum = c0 + c1 + c2 + c3;
    sc0[t] = tsum; __syncthreads();
    int* src = sc0; int* dst = sc1;
    for (int off = 1; off < 256; off <<= 1) {
        int x = src[t]; if (t >= off) x += src[t - off];
        dst[t] = x; __syncthreads();
        int* tmp = src; src = dst; dst = tmp;
    }
    int exclT = src[t] - tsum;
    int e0 = exclT, e1 = e0 + c0, e2 = e1 + c1, e3 = e2 + c2;
    excl[t * 4] = e0; excl[t * 4 + 1] = e1; excl[t * 4 + 2] = e2; excl[t * 4 + 3] = e3;
    // pos = inclusive ends in global col coords (sequential writes)
    {
        int i = t * 4;
        if (i < ndst)     pos[dstbase + i]     = colbase + e1;
        if (i + 1 < ndst) pos[dstbase + i + 1] = colbase + e2;
        if (i + 2 < ndst) pos[dstbase + i + 2] = colbase + e3;
        if (i + 3 < ndst) pos[dstbase + i + 3] = colbase + e3 + c3;
    }
    __syncthreads();
    for (int i = t; i < 1024; i += 256) cnt[i] = 0;
    __syncthreads();
    for (int i = t; i < count; i += 256) {
        u32 rc = rec[i];
        int dl = rc & 1023;
        int rk = atomicAdd(&cnt[dl], 1);
        col[colbase + excl[dl] + rk] = (int)(rc >> 10);
    }
}

// Gather-mean, TWO destinations per wave (32 lanes each), both node sides in
// one grid. Per destination: 2 groups x 16 lanes; each lane reads 16 B of an
// edge-row; 4 loads in flight per lane (8 edges/dest/iteration).
// Edge indices come from DIRECT L1-hot col[] loads (all 16 lanes of a group
// hit the same 64-B line) — iteration k+1's col loads are independent of
// iteration k's feature loads, so they pipeline under vmcnt. Out-of-segment
// indices read adjacent valid memory and are cndmask'd to the ZERO ROW
// (exact 0.0f contribution; FP summation order identical to prior rounds).
// Single shfl_xor(16) reduce; group 0 packs bf16 out.
__global__ __launch_bounds__(256)
void gather_mean2(const u16* __restrict__ featA, const int* __restrict__ colA,
                  const int* __restrict__ posA, u16* __restrict__ outA, int ndstA, int nwaveA, int zrowA,
                  const u16* __restrict__ featB, const int* __restrict__ colB,
                  const int* __restrict__ posB, u16* __restrict__ outB, int ndstB, int zrowB) {
    int gw = (blockIdx.x * blockDim.x + threadIdx.x) >> 6;
    const u16* feat; const int* col; const int* pos; u16* outm; int ndst, dbase, zrow;
    if (gw < nwaveA) {
        feat = featA; col = colA; pos = posA; outm = outA; ndst = ndstA; dbase = gw * 2; zrow = zrowA;
    } else {
        feat = featB; col = colB; pos = posB; outm = outB; ndst = ndstB; dbase = (gw - nwaveA) * 2; zrow = zrowB;
    }
    int lane = threadIdx.x & 63;
    int h = lane >> 5, l5 = lane & 31, g2 = l5 >> 4, s = l5 & 15;
    int d = dbase + h;
    if (d >= ndst) return;

    int start = (d == 0) ? 0 : pos[d - 1];
    int end = pos[d];
    int deg = end - start;

    float acc[8];
#pragma unroll
    for (int k = 0; k < 8; ++k) acc[k] = 0.f;

#define LDROW(idx) (*(const uint4*)(feat + (size_t)(idx) * 128 + s * 8))
#define ACC4(a, b, c, dd) \
    acc[0] += (bflo(a.x) + bflo(b.x)) + (bflo(c.x) + bflo(dd.x)); \
    acc[1] += (bfhi(a.x) + bfhi(b.x)) + (bfhi(c.x) + bfhi(dd.x)); \
    acc[2] += (bflo(a.y) + bflo(b.y)) + (bflo(c.y) + bflo(dd.y)); \
    acc[3] += (bfhi(a.y) + bfhi(b.y)) + (bfhi(c.y) + bfhi(dd.y)); \
    acc[4] += (bflo(a.z) + bflo(b.z)) + (bflo(c.z) + bflo(dd.z)); \
    acc[5] += (bfhi(a.z) + bfhi(b.z)) + (bfhi(c.z) + bfhi(dd.z)); \
    acc[6] += (bflo(a.w) + bflo(b.w)) + (bflo(c.w) + bflo(dd.w)); \
    acc[7] += (bfhi(a.w) + bfhi(b.w)) + (bfhi(c.w) + bfhi(dd.w));

    if (deg > 0) {
        int mdeg = min(deg, 32);
        const int* cbase = col + start;
        for (int e0 = 0; e0 < mdeg; e0 += 8) {
            int i0 = e0 + g2, i1 = e0 + 2 + g2, i2 = e0 + 4 + g2, i3 = e0 + 6 + g2;
            // reads beyond the segment (i >= deg, i < 32) land in the next
            // segment / adjacent arrays — valid memory, replaced by zrow.
            int t0 = cbase[i0], t1 = cbase[i1], t2 = cbase[i2], t3 = cbase[i3];
            int x0 = (i0 < deg) ? t0 : zrow, x1 = (i1 < deg) ? t1 : zrow;
            int x2 = (i2 < deg) ? t2 : zrow, x3 = (i3 < deg) ? t3 : zrow;
            uint4 v0 = LDROW(x0), v1 = LDROW(x1), v2 = LDROW(x2), v3 = LDROW(x3);
            ACC4(v0, v1, v2, v3)
        }
        // rare path: degrees beyond 32 (repo tail of Poisson(15))
        for (int e = 32 + g2; e < deg; e += 2) {
            int idx = cbase[e];
            uint4 v = LDROW(idx);
            acc[0] += bflo(v.x); acc[1] += bfhi(v.x);
            acc[2] += bflo(v.y); acc[3] += bfhi(v.y);
            acc[4] += bflo(v.z); acc[5] += bfhi(v.z);
            acc[6] += bflo(v.w); acc[7] += bfhi(v.w);
        }
        // combine the 2 group partials within each 32-lane half
#pragma unroll
        for (int k = 0; k < 8; ++k) acc[k] += __shfl_xor(acc[k], 16, 64);
    }
#undef LDROW
#undef ACC4

    if (g2 == 0) {
        float inv = (deg > 0) ? 1.0f / (float)deg : 0.f;
        uint4 o;
        o.x = (u32)f2bf(acc[0] * inv) | ((u32)f2bf(acc[1] * inv) << 16);
        o.y = (u32)f2bf(acc[2] * inv) | ((u32)f2bf(acc[3] * inv) << 16);
        o.z = (u32)f2bf(acc[4] * inv) | ((u32)f2bf(acc[5] * inv) << 16);
        o.w = (u32)f2bf(acc[6] * inv) | ((u32)f2bf(acc[7] * inv) << 16);
        *(uint4*)(outm + (size_t)d * 128 + s * 8) = o;
    }
}

// MFMA transform, both node sides in one grid, ONE 64-row tile per block
// (4688 blocks = 18.3/CU: tail quantization ~5%; measured faster than
// multi-tile blocks whose 4.6-blocks/CU grid had a ~20% residency tail).
// out[N x 128] = [mean|x] @ [Wl;Wr] + bias (opt relu).
__global__ __launch_bounds__(256)
void transform_both(const u16* __restrict__ A_A, const u16* __restrict__ X_A,
                    const u16* __restrict__ Wt_A, const float* __restrict__ b_A,
                    u16* __restrict__ obf_A, float* __restrict__ of32_A, int N_A, int nblkA,
                    const u16* __restrict__ A_B, const u16* __restrict__ X_B,
                    const u16* __restrict__ Wt_B, const float* __restrict__ b_B,
                    u16* __restrict__ obf_B, float* __restrict__ of32_B, int N_B,
                    int do_relu) {
    __shared__ __align__(16) u16 sA[64][264];
    const u16* A; const u16* X; const u16* Wt; const float* bias;
    u16* out_bf; float* out_f32; int N, base;
    if ((int)blockIdx.x < nblkA) {
        A = A_A; X = X_A; Wt = Wt_A; bias = b_A; out_bf = obf_A; out_f32 = of32_A;
        N = N_A; base = blockIdx.x * 64;
    } else {
        A = A_B; X = X_B; Wt = Wt_B; bias = b_B; out_bf = obf_B; out_f32 = of32_B;
        N = N_B; base = (blockIdx.x - nblkA) * 64;
    }
    int tid = threadIdx.x;
    int w = tid >> 6, lane = tid & 63;
    int q = lane >> 4, n = lane & 15;
    int nb = w * 32;

    bf16x8 bfrag[2][8];
#pragma unroll
    for (int nt = 0; nt < 2; ++nt)
#pragma unroll
        for (int ks = 0; ks < 8; ++ks)
            bfrag[nt][ks] = as_bf16x8(*(const uint4*)(Wt + (size_t)(nb + nt * 16 + n) * 256 + ks * 32 + q * 8));
    float bv[2] = { bias[nb + n], bias[nb + 16 + n] };

    {
        int r = tid >> 2, c = tid & 3;
        int node = base + r;
        uint4 z = make_uint4(0, 0, 0, 0);
        uint4 va[4], vx[4];
        if (node < N) {
            const uint4* pa = (const uint4*)(A + (size_t)node * 128 + c * 32);
            const uint4* px = (const uint4*)(X + (size_t)node * 128 + c * 32);
#pragma unroll
            for (int j = 0; j < 4; ++j) { va[j] = pa[j]; vx[j] = px[j]; }
        } else {
#pragma unroll
            for (int j = 0; j < 4; ++j) { va[j] = z; vx[j] = z; }
        }
#pragma unroll
        for (int j = 0; j < 4; ++j) {
            *(uint4*)&sA[r][c * 32 + j * 8] = va[j];
            *(uint4*)&sA[r][128 + c * 32 + j * 8] = vx[j];
        }
    }
    __syncthreads();

    f32x4 zz = { 0.f, 0.f, 0.f, 0.f };
    f32x4 acc[4][2];
#pragma unroll
    for (int mt = 0; mt < 4; ++mt) { acc[mt][0] = zz; acc[mt][1] = zz; }

#pragma unroll
    for (int ks = 0; ks < 8; ++ks)
#pragma unroll
        for (int mt = 0; mt < 4; ++mt) {
            bf16x8 af = *(const bf16x8*)&sA[mt * 16 + n][ks * 32 + q * 8];
            acc[mt][0] = __builtin_amdgcn_mfma_f32_16x16x32_bf16(af, bfrag[0][ks], acc[mt][0], 0, 0, 0);
            acc[mt][1] = __builtin_amdgcn_mfma_f32_16x16x32_bf16(af, bfrag[1][ks], acc[mt][1], 0, 0, 0);
        }

#pragma unroll
    for (int mt = 0; mt < 4; ++mt) {
        int row0 = base + mt * 16 + q * 4;
#pragma unroll
        for (int nt = 0; nt < 2; ++nt) {
            int colg = nb + nt * 16 + n;
#pragma unroll
            for (int r = 0; r < 4; ++r) {
                int row = row0 + r;
                if (row < N) {
                    float v = acc[mt][nt][r] + bv[nt];
                    if (do_relu) v = fmaxf(v, 0.f);
                    if (out_bf) out_bf[(size_t)row * 128 + colg] = f2bf(v);
                    else        out_f32[(size_t)row * 128 + colg] = v;
                }
            }
        }
    }
}

extern "C" void kernel_launch(void* const* d_in, const int* in_sizes, int n_in,
                              void* d_out, int out_size, void* d_ws, size_t ws_size,
                              hipStream_t stream) {
    const float* x_user = (const float*)d_in[0];
    const float* x_repo = (const float*)d_in[1];
    const u32* edges = (const u32*)d_in[2];
    const float* Wl1s = (const float*)d_in[3], *bl1s = (const float*)d_in[4], *Wr1s = (const float*)d_in[5];
    const float* Wl1r = (const float*)d_in[6], *bl1r = (const float*)d_in[7], *Wr1r = (const float*)d_in[8];
    const float* Wl2s = (const float*)d_in[9], *bl2s = (const float*)d_in[10], *Wr2s = (const float*)d_in[11];
    const float* Wl2r = (const float*)d_in[12], *bl2r = (const float*)d_in[13], *Wr2r = (const float*)d_in[14];

    float* out_user = (float*)d_out;
    float* out_repo = (float*)d_out + (size_t)NUSER * 128;

    if (ws_size < WS_NEEDED) {
        hipLaunchKernelGGL(sentinel_kernel, dim3(1), dim3(256), 0, stream, out_user);
        return;
    }

    char* ws = (char*)d_ws;
    u32* rec_r = (u32*)(ws + OFF_RECR);
    u32* rec_u = (u32*)(ws + OFF_RECU);
    u16* B0 = (u16*)(ws + OFF_B0);
    u16* B1 = (u16*)(ws + OFF_B1);
    u16* B2 = (u16*)(ws + OFF_B2);
    u16* B3 = (u16*)(ws + OFF_B3);
    int* col_r = (int*)(ws + OFF_COLR);
    int* col_u = (int*)(ws + OFF_COLU);
    int* pos_r = (int*)(ws + OFF_POSR);
    int* pos_u = (int*)(ws + OFF_POSU);
    u16* wt1s = (u16*)(ws + OFF_WT);
    u16* wt1r = wt1s + 32768;
    u16* wt2s = wt1r + 32768;
    u16* wt2r = wt2s + 32768;
    int* gcur_r = (int*)(ws + OFF_CUR);          // 400 B
    int* gcur_u = (int*)(ws + OFF_CUR + 400);    // 800 B
    int* cb_r   = (int*)(ws + OFF_CUR + 1200);   // 400 B
    int* cb_u   = (int*)(ws + OFF_CUR + 1600);   // 800 B

    const int nblkR = (NREPO + 63) / 64;   // 1563
    const int nblkU = (NUSER + 63) / 64;   // 3125
    const int nwaveR = NREPO / 2;          // 50000 (2 dests/wave)
    const int nwaveU = NUSER / 2;          // 100000
    const int gblk = (nwaveR + nwaveU) / 4;  // 37500 blocks, 4 waves each

    // init (CSR counters + zero rows), then CSR build (binned, L2-confined scatter)
    hipLaunchKernelGGL(init_kernel, dim3(1), dim3(320), 0, stream, ws);
    hipLaunchKernelGGL(passA_bin, dim3(367), dim3(256), 0, stream, edges, rec_r, rec_u, gcur_r, gcur_u);
    hipLaunchKernelGGL(bucket_scan, dim3(1), dim3(256), 0, stream, gcur_r, gcur_u, cb_r, cb_u);
    hipLaunchKernelGGL(passB_build, dim3(RB + UB), dim3(256), 0, stream,
                       rec_r, rec_u, gcur_r, gcur_u, cb_r, cb_u, col_r, col_u, pos_r, pos_u);

    // weight prep + input converts (records dead from here; B-regions live)
    hipLaunchKernelGGL(wprep4_kernel, dim3(512), dim3(256), 0, stream,
                       Wl1s, Wr1s, Wl1r, Wr1r, Wl2s, Wr2s, Wl2r, Wr2r, wt1s);
    hipLaunchKernelGGL(cvt_bf16_both, dim3(37500), dim3(256), 0, stream,
                       (const float4*)x_user, (uint2*)B2, NUSER * 128 / 4,
                       (const float4*)x_repo, (uint2*)B3, NREPO * 128 / 4);

    // Layer 1: merged gathers, merged transforms (in-place mean -> hidden, relu)
    hipLaunchKernelGGL(gather_mean2, dim3(gblk), dim3(256), 0, stream,
                       B2, col_r, pos_r, B1, NREPO, nwaveR, NUSER,
                       B3, col_u, pos_u, B0, NUSER, NREPO);
    hipLaunchKernelGGL(transform_both, dim3(nblkR + nblkU), dim3(256), 0, stream,
                       B1, B3, wt1s, bl1s, B1, (float*)nullptr, NREPO, nblkR,
                       B0, B2, wt1r, bl1r, B0, (float*)nullptr, NUSER,
                       1);

    // Layer 2: gathers over hiddens, transforms write fp32 d_out
    hipLaunchKernelGGL(gather_mean2, dim3(gblk), dim3(256), 0, stream,
                       B0, col_r, pos_r, B3, NREPO, nwaveR, NUSER,
                       B1, col_u, pos_u, B2, NUSER, NREPO);
    hipLaunchKernelGGL(transform_both, dim3(nblkR + nblkU), dim3(256), 0, stream,
                       B3, B1, wt2s, bl2s, (u16*)nullptr, out_repo, NREPO, nblkR,
                       B2, B0, wt2r, bl2r, (u16*)nullptr, out_user, NUSER,
                       0);
}